// Round 4
// baseline (206.715 us; speedup 1.0000x reference)
//
#include <hip/hip_runtime.h>
#include <math.h>

#define HDIM 256
#define PDIM 256
#define BATCH 8
#define LSEQ 4096
#define MTOT (BATCH * LSEQ)   // 32768
#define NCHUNK 128
#define CHLEN 32              // NCHUNK*CHLEN == LSEQ

typedef __attribute__((ext_vector_type(8))) short bf16x8;   // 8 bf16 = 4 VGPRs
typedef __attribute__((ext_vector_type(4))) float f32x4;

__device__ __forceinline__ unsigned short f2bf(float f) {
    union { float f; unsigned int u; } v; v.f = f;
    unsigned int r = v.u + 0x7FFFu + ((v.u >> 16) & 1u);   // RNE
    return (unsigned short)(r >> 16);
}
__device__ __forceinline__ float bf2f(unsigned int lo16) {
    union { unsigned int u; float f; } v; v.u = lo16 << 16;
    return v.f;
}

// ---------------- merged setup: par + W1t + W2t in one launch ----------------
// par floats: [0:512) a  [512:1024) coef  [1024:1536) a^CHLEN  (interleaved r,i)
// W1t[n][k]: n=2p -> Re(coef_p * B_tilde[p][k]); n=2p+1 -> Im. (bf16, [512][256])
// W2t[h][2p] = Cr[h][p]; W2t[h][2p+1] = -Ci[h][p]. (bf16, [256][512])
__global__ void wpack_k(const float* __restrict__ llr, const float* __restrict__ lim,
                        const float* __restrict__ ldl,
                        const float* __restrict__ Br, const float* __restrict__ Bi,
                        const float* __restrict__ Cr, const float* __restrict__ Ci,
                        unsigned short* __restrict__ W1t, unsigned short* __restrict__ W2t,
                        float* __restrict__ par) {
    int h = threadIdx.x;
    if (blockIdx.x < PDIM) {
        int p = blockIdx.x;
        float er = expf(llr[p]);
        float im = lim[p];
        float d  = expf(ldl[p]);
        float zr = -er * d, zi = im * d;
        float ea = expf(zr);
        float sz, cz; sincosf(zi, &sz, &cz);
        float ar = ea * cz, ai = ea * sz;
        float dr = -er, di = im;
        float den = dr * dr + di * di;
        float nr = ar - 1.0f, ni = ai;
        float cr = (nr * dr + ni * di) / den;
        float ci = (ni * dr - nr * di) / den;
        float br = Br[p * HDIM + h], bi = Bi[p * HDIM + h];
        W1t[(2 * p) * HDIM + h]     = f2bf(cr * br - ci * bi);
        W1t[(2 * p + 1) * HDIM + h] = f2bf(cr * bi + ci * br);
    } else if (blockIdx.x < 2 * PDIM) {
        int p = blockIdx.x - PDIM;
        W2t[h * (2 * PDIM) + 2 * p]     = f2bf(Cr[h * PDIM + p]);
        W2t[h * (2 * PDIM) + 2 * p + 1] = f2bf(-Ci[h * PDIM + p]);
    } else {
        int p = h;
        float er = expf(llr[p]);
        float im = lim[p];
        float d  = expf(ldl[p]);
        float zr = -er * d, zi = im * d;
        float ea = expf(zr);
        float sz, cz; sincosf(zi, &sz, &cz);
        float ar = ea * cz, ai = ea * sz;
        float dr = -er, di = im;
        float den = dr * dr + di * di;
        float nr = ar - 1.0f, ni = ai;
        float cr = (nr * dr + ni * di) / den;
        float ci = (ni * dr - nr * di) / den;
        float eC = expf((float)CHLEN * zr);
        float sC, cC;
        sincosf((float)CHLEN * zi, &sC, &cC);
        par[2 * p]            = ar;
        par[2 * p + 1]        = ai;
        par[512 + 2 * p]      = cr;
        par[512 + 2 * p + 1]  = ci;
        par[1024 + 2 * p]     = eC * cC;
        par[1024 + 2 * p + 1] = eC * sC;
    }
}

// ---------------- fused LayerNorm -> bf16 h ----------------
__global__ void ln_k(const float* __restrict__ u, unsigned short* __restrict__ hbf,
                     const float* __restrict__ gamma, const float* __restrict__ beta) {
    __shared__ float gS[HDIM], bS[HDIM];
    int t = threadIdx.x;
    gS[t] = gamma[t]; bS[t] = beta[t];
    int lane = t & 63, wv = t >> 6;
    int row = blockIdx.x * 4 + wv;
    float4 v = *(const float4*)(u + (size_t)row * HDIM + lane * 4);
    float s  = v.x + v.y + v.z + v.w;
    float sq = v.x * v.x + v.y * v.y + v.z * v.z + v.w * v.w;
    #pragma unroll
    for (int o = 1; o < 64; o <<= 1) { s += __shfl_xor(s, o); sq += __shfl_xor(sq, o); }
    float mu = s * (1.0f / HDIM);
    float rs = rsqrtf(sq * (1.0f / HDIM) - mu * mu + 1e-5f);
    __syncthreads();
    int c = lane * 4;
    ushort4 o;
    o.x = f2bf((v.x - mu) * rs * gS[c + 0] + bS[c + 0]);
    o.y = f2bf((v.y - mu) * rs * gS[c + 1] + bS[c + 1]);
    o.z = f2bf((v.z - mu) * rs * gS[c + 2] + bS[c + 2]);
    o.w = f2bf((v.w - mu) * rs * gS[c + 3] + bS[c + 3]);
    *(ushort4*)(hbf + (size_t)row * HDIM + c) = o;
}

// ---------------- GEMM1: Bu[32768][512] = h[32768][256] @ W1t^T ----------------
// B-resident structure: entire B-tile [128 N][256 K] (64 KB) staged ONCE into
// swizzled LDS; A-fragments loaded directly global->VGPR in MFMA layout
// (16B/lane, 64B-coalesced). Main loop has NO barriers and NO LDS staging:
// compiler freely hoists the independent fa loads across MFMAs.
// 512 thr = 8 waves (4 in M x 2 in N), block tile 256M x 128N, grid (4,128).
// Bs swizzle: 16B-chunk c of row n stored at c ^ (n&7) -> ds_read_b128 worst
// case 2-way (free). XCD remap keeps the 4 bn-siblings of one A-panel on one XCD.
__launch_bounds__(512, 4)
__global__ void gemm1_k(const unsigned short* __restrict__ A,
                        const unsigned short* __restrict__ W1t,
                        unsigned short* __restrict__ Bu) {
    __shared__ __align__(16) unsigned short Bs[128 * 256];   // 64 KB
    const int t = threadIdx.x;
    const int lane = t & 63, w = t >> 6;

    const int nbn  = (int)gridDim.x;                         // 4
    const int flat = (int)blockIdx.y * nbn + (int)blockIdx.x;
    const int nwg  = nbn * (int)gridDim.y;                   // 512
    const int tile = (flat & 7) * (nwg >> 3) + (flat >> 3);
    const int bn = tile % nbn, bm = tile / nbn;

    // stage Bs once: 4096 16B-chunks, 8 per thread, coalesced reads
    #pragma unroll
    for (int k = 0; k < 8; k++) {
        const int ci = t * 8 + k;
        const int n = ci >> 5, c = ci & 31;                  // 32 chunks per 256-elem row
        uint4 v = *(const uint4*)(W1t + (size_t)(bn * 128 + n) * HDIM + c * 8);
        *(uint4*)&Bs[n * 256 + ((c ^ (n & 7)) * 8)] = v;
    }

    const int wm = (w >> 1) * 64, wn = (w & 1) * 64;
    const int mrow = lane & 15, cch = lane >> 4;
    const unsigned short* gA = A + (size_t)(bm * 256 + wm + mrow) * HDIM + cch * 8;

    // prefetch k-step 0 A-fragments before the staging barrier
    bf16x8 fa[4];
    #pragma unroll
    for (int i = 0; i < 4; i++) fa[i] = *(const bf16x8*)(gA + i * 16 * HDIM);

    f32x4 acc[4][4] = {};
    __syncthreads();                                         // Bs ready

    #pragma unroll
    for (int tt = 0; tt < HDIM / 32; tt++) {                 // 8 steps, no barriers
        bf16x8 fnext[4];
        if (tt + 1 < HDIM / 32) {
            #pragma unroll
            for (int i = 0; i < 4; i++)
                fnext[i] = *(const bf16x8*)(gA + i * 16 * HDIM + (tt + 1) * 32);
        }
        bf16x8 fb[4];
        #pragma unroll
        for (int j = 0; j < 4; j++) {
            const int n = wn + j * 16 + mrow;
            fb[j] = *(const bf16x8*)&Bs[n * 256 + (((tt * 4 + cch) ^ (n & 7)) * 8)];
        }
        #pragma unroll
        for (int i = 0; i < 4; i++)
            #pragma unroll
            for (int j = 0; j < 4; j++)
                acc[i][j] = __builtin_amdgcn_mfma_f32_16x16x32_bf16(fa[i], fb[j], acc[i][j], 0, 0, 0);
        #pragma unroll
        for (int i = 0; i < 4; i++) fa[i] = fnext[i];
    }

    // C/D layout: col = lane&15, row = (lane>>4)*4 + reg
    const int r0 = (lane >> 4) * 4, c0 = lane & 15;
    #pragma unroll
    for (int i = 0; i < 4; i++) {
        #pragma unroll
        for (int r = 0; r < 4; r++) {
            const size_t rowoff = (size_t)(bm * 256 + wm + i * 16 + r0 + r) * 512;
            #pragma unroll
            for (int j = 0; j < 4; j++)
                Bu[rowoff + bn * 128 + wn + j * 16 + c0] = f2bf(acc[i][j][r]);
        }
    }
}

// ---------------- GEMM2: out = u + gelu( x[32768][512] @ W2t^T ) ----------------
// Same B-resident structure. B-tile [64 N][512 K] = 64 KB. Block tile
// 256M x 64N, 8 waves (4 in M x 2 in N, wave 64x32), 16 k-steps, grid (4,128).
__launch_bounds__(512, 4)
__global__ void gemm2_k(const unsigned short* __restrict__ X,
                        const unsigned short* __restrict__ W2t,
                        const float* __restrict__ u, float* __restrict__ out) {
    __shared__ __align__(16) unsigned short Bs[64 * 512];    // 64 KB
    const int t = threadIdx.x;
    const int lane = t & 63, w = t >> 6;

    const int nbn  = (int)gridDim.x;                         // 4
    const int flat = (int)blockIdx.y * nbn + (int)blockIdx.x;
    const int nwg  = nbn * (int)gridDim.y;                   // 512
    const int tile = (flat & 7) * (nwg >> 3) + (flat >> 3);
    const int bn = tile % nbn, bm = tile / nbn;

    // stage Bs once: 64 rows x 64 chunks = 4096 chunks, 8 per thread
    #pragma unroll
    for (int k = 0; k < 8; k++) {
        const int ci = t * 8 + k;
        const int n = ci >> 6, c = ci & 63;                  // 64 chunks per 512-elem row
        uint4 v = *(const uint4*)(W2t + (size_t)(bn * 64 + n) * 512 + c * 8);
        *(uint4*)&Bs[n * 512 + ((c ^ (n & 7)) * 8)] = v;
    }

    const int wm = (w >> 1) * 64, wn = (w & 1) * 32;
    const int mrow = lane & 15, cch = lane >> 4;
    const unsigned short* gA = X + (size_t)(bm * 256 + wm + mrow) * 512 + cch * 8;

    bf16x8 fa[4];
    #pragma unroll
    for (int i = 0; i < 4; i++) fa[i] = *(const bf16x8*)(gA + i * 16 * 512);

    f32x4 acc[4][2] = {};
    __syncthreads();

    #pragma unroll
    for (int tt = 0; tt < 16; tt++) {                        // K=512, no barriers
        bf16x8 fnext[4];
        if (tt + 1 < 16) {
            #pragma unroll
            for (int i = 0; i < 4; i++)
                fnext[i] = *(const bf16x8*)(gA + i * 16 * 512 + (tt + 1) * 32);
        }
        bf16x8 fb[2];
        #pragma unroll
        for (int j = 0; j < 2; j++) {
            const int n = wn + j * 16 + mrow;
            fb[j] = *(const bf16x8*)&Bs[n * 512 + (((tt * 4 + cch) ^ (n & 7)) * 8)];
        }
        #pragma unroll
        for (int i = 0; i < 4; i++)
            #pragma unroll
            for (int j = 0; j < 2; j++)
                acc[i][j] = __builtin_amdgcn_mfma_f32_16x16x32_bf16(fa[i], fb[j], acc[i][j], 0, 0, 0);
        #pragma unroll
        for (int i = 0; i < 4; i++) fa[i] = fnext[i];
    }

    // epilogue: out = u + gelu(acc), fp32, N = 256
    const int r0 = (lane >> 4) * 4, c0 = lane & 15;
    #pragma unroll
    for (int i = 0; i < 4; i++) {
        #pragma unroll
        for (int r = 0; r < 4; r++) {
            const size_t rowoff = (size_t)(bm * 256 + wm + i * 16 + r0 + r) * HDIM;
            #pragma unroll
            for (int j = 0; j < 2; j++) {
                const int col = bn * 64 + wn + j * 16 + c0;
                float y = acc[i][j][r];
                float z = 0.7978845608f * fmaf(0.044715f * y * y, y, y);
                float e = __expf(2.0f * z);
                float th = 1.0f - 2.0f / (e + 1.0f);
                float g = 0.5f * y * (1.0f + th);
                out[rowoff + col] = u[rowoff + col] + g;
            }
        }
    }
}

// ---------------- chunked diagonal complex scan over bf16 Bu ----------------
__global__ void scan_reduce_k(const unsigned short* __restrict__ Bu,
                              const float* __restrict__ par, float* __restrict__ last) {
    int t = threadIdx.x;
    int lane = t & 63, g = t >> 6;
    int c = blockIdx.x * 4 + g, b = blockIdx.y;
    int p0 = lane * 4;
    float4 a01 = *(const float4*)(par + 2 * p0);       // ar0 ai0 ar1 ai1
    float4 a23 = *(const float4*)(par + 2 * p0 + 4);   // ar2 ai2 ar3 ai3
    float ar[4] = {a01.x, a01.z, a23.x, a23.z};
    float ai[4] = {a01.y, a01.w, a23.y, a23.w};
    float xr[4] = {0.f, 0.f, 0.f, 0.f}, xi[4] = {0.f, 0.f, 0.f, 0.f};
    const uint4* q = (const uint4*)(Bu + ((size_t)b * LSEQ + (size_t)c * CHLEN) * 512) + lane;
    #pragma unroll 8
    for (int j = 0; j < CHLEN; j++) {
        uint4 v = q[(size_t)j * 64];   // row stride 512 bf16 = 64 uint4
        unsigned int vv[4] = {v.x, v.y, v.z, v.w};
        #pragma unroll
        for (int k = 0; k < 4; k++) {
            float vr = bf2f(vv[k] & 0xFFFFu), vi = bf2f(vv[k] >> 16);
            float nr = fmaf(ar[k], xr[k], fmaf(-ai[k], xi[k], vr));
            float ni = fmaf(ar[k], xi[k], fmaf(ai[k], xr[k], vi));
            xr[k] = nr; xi[k] = ni;
        }
    }
    float* lp = last + ((size_t)b * NCHUNK + c) * 512 + 2 * p0;
    *(float4*)lp       = make_float4(xr[0], xi[0], xr[1], xi[1]);
    *(float4*)(lp + 4) = make_float4(xr[2], xi[2], xr[3], xi[3]);
}

__global__ void scan_carry_k(const float* __restrict__ last, float* __restrict__ prefix,
                             const float* __restrict__ par) {
    int p = threadIdx.x, b = blockIdx.x;
    float Ar = par[1024 + 2 * p], Ai = par[1024 + 2 * p + 1];  // a^CHLEN
    float Pr = 0.0f, Pi = 0.0f;
    const float2* lp = (const float2*)(last + (size_t)b * NCHUNK * 512) + p;
    float2* pp = (float2*)(prefix + (size_t)b * NCHUNK * 512) + p;
    for (int c0 = 0; c0 < NCHUNK; c0 += 16) {
        float2 v[16];
        #pragma unroll
        for (int j = 0; j < 16; j++) v[j] = lp[(size_t)(c0 + j) * 256];
        #pragma unroll
        for (int j = 0; j < 16; j++) {
            pp[(size_t)(c0 + j) * 256] = make_float2(Pr, Pi);
            float nr = fmaf(Ar, Pr, fmaf(-Ai, Pi, v[j].x));
            float ni = fmaf(Ar, Pi, fmaf(Ai, Pr, v[j].y));
            Pr = nr; Pi = ni;
        }
    }
}

__global__ void scan_apply_k(unsigned short* __restrict__ Bu, const float* __restrict__ par,
                             const float* __restrict__ prefix) {
    int t = threadIdx.x;
    int lane = t & 63, g = t >> 6;
    int c = blockIdx.x * 4 + g, b = blockIdx.y;
    int p0 = lane * 4;
    float4 a01 = *(const float4*)(par + 2 * p0);
    float4 a23 = *(const float4*)(par + 2 * p0 + 4);
    float ar[4] = {a01.x, a01.z, a23.x, a23.z};
    float ai[4] = {a01.y, a01.w, a23.y, a23.w};
    const float* pf = prefix + ((size_t)b * NCHUNK + c) * 512 + 2 * p0;
    float4 P01 = *(const float4*)pf;
    float4 P23 = *(const float4*)(pf + 4);
    float xr[4] = {P01.x, P01.z, P23.x, P23.z};
    float xi[4] = {P01.y, P01.w, P23.y, P23.w};
    uint4* q = (uint4*)(Bu + ((size_t)b * LSEQ + (size_t)c * CHLEN) * 512) + lane;
    #pragma unroll 8
    for (int j = 0; j < CHLEN; j++) {
        uint4 v = q[(size_t)j * 64];
        unsigned int vv[4] = {v.x, v.y, v.z, v.w};
        #pragma unroll
        for (int k = 0; k < 4; k++) {
            float vr = bf2f(vv[k] & 0xFFFFu), vi = bf2f(vv[k] >> 16);
            float nr = fmaf(ar[k], xr[k], fmaf(-ai[k], xi[k], vr));
            float ni = fmaf(ar[k], xi[k], fmaf(ai[k], xr[k], vi));
            xr[k] = nr; xi[k] = ni;
            vv[k] = (unsigned int)f2bf(nr) | ((unsigned int)f2bf(ni) << 16);
        }
        uint4 o; o.x = vv[0]; o.y = vv[1]; o.z = vv[2]; o.w = vv[3];
        q[(size_t)j * 64] = o;
    }
}

extern "C" void kernel_launch(void* const* d_in, const int* in_sizes, int n_in,
                              void* d_out, int out_size, void* d_ws, size_t ws_size,
                              hipStream_t stream) {
    const float* u   = (const float*)d_in[0];
    const float* llr = (const float*)d_in[1];
    const float* lim = (const float*)d_in[2];
    const float* Br  = (const float*)d_in[3];
    const float* Bi  = (const float*)d_in[4];
    const float* Cr  = (const float*)d_in[5];
    const float* Ci  = (const float*)d_in[6];
    const float* ldl = (const float*)d_in[7];
    const float* gam = (const float*)d_in[8];
    const float* bet = (const float*)d_in[9];
    float* out = (float*)d_out;

    float* ws     = (float*)d_ws;
    float* par    = ws;                                     // 2048 floats
    float* last   = ws + 2048;                              // 8*128*512 floats (2 MB)
    float* prefix = last + (size_t)BATCH * NCHUNK * 512;    // 2 MB
    unsigned short* W1t = (unsigned short*)(prefix + (size_t)BATCH * NCHUNK * 512);
    unsigned short* W2t = W1t + 512 * HDIM;                 // [256][512]
    unsigned short* hbf = W2t + HDIM * 512;                 // [32768][256] bf16
    unsigned short* Bu  = hbf + (size_t)MTOT * HDIM;        // [32768][512] bf16 (in-place -> x)

    ln_k<<<MTOT / 4, 256, 0, stream>>>(u, hbf, gam, bet);
    wpack_k<<<2 * PDIM + 1, HDIM, 0, stream>>>(llr, lim, ldl, Br, Bi, Cr, Ci, W1t, W2t, par);

    // GEMM1: B-resident, barrier-free main loop
    gemm1_k<<<dim3(4, MTOT / 256), 512, 0, stream>>>(hbf, W1t, Bu);

    scan_reduce_k<<<dim3(NCHUNK / 4, BATCH), 256, 0, stream>>>(Bu, par, last);
    scan_carry_k<<<BATCH, PDIM, 0, stream>>>(last, prefix, par);
    scan_apply_k<<<dim3(NCHUNK / 4, BATCH), 256, 0, stream>>>(Bu, par, prefix);

    // GEMM2: B-resident, barrier-free main loop, fused u + gelu epilogue
    gemm2_k<<<dim3(4, MTOT / 256), 512, 0, stream>>>(Bu, W2t, u, out);
}

// Round 5
// 193.537 us; speedup vs baseline: 1.0681x; 1.0681x over previous
//
#include <hip/hip_runtime.h>
#include <math.h>

#define HDIM 256
#define PDIM 256
#define BATCH 8
#define LSEQ 4096
#define MTOT (BATCH * LSEQ)   // 32768
#define NCHUNK 128
#define CHLEN 32              // NCHUNK*CHLEN == LSEQ

typedef __attribute__((ext_vector_type(8))) short bf16x8;   // 8 bf16 = 4 VGPRs
typedef __attribute__((ext_vector_type(4))) float f32x4;

__device__ __forceinline__ unsigned short f2bf(float f) {
    union { float f; unsigned int u; } v; v.f = f;
    unsigned int r = v.u + 0x7FFFu + ((v.u >> 16) & 1u);   // RNE
    return (unsigned short)(r >> 16);
}
__device__ __forceinline__ float bf2f(unsigned int lo16) {
    union { unsigned int u; float f; } v; v.u = lo16 << 16;
    return v.f;
}

// ---------------- merged setup: par + W1t + W2t in one launch ----------------
// par floats: [0:512) a  [512:1024) coef  [1024:1536) a^CHLEN  (interleaved r,i)
// W1t[n][k]: n=2p -> Re(coef_p * B_tilde[p][k]); n=2p+1 -> Im. (bf16, [512][256])
// W2t[h][2p] = Cr[h][p]; W2t[h][2p+1] = -Ci[h][p]. (bf16, [256][512])
__global__ void wpack_k(const float* __restrict__ llr, const float* __restrict__ lim,
                        const float* __restrict__ ldl,
                        const float* __restrict__ Br, const float* __restrict__ Bi,
                        const float* __restrict__ Cr, const float* __restrict__ Ci,
                        unsigned short* __restrict__ W1t, unsigned short* __restrict__ W2t,
                        float* __restrict__ par) {
    int h = threadIdx.x;
    if (blockIdx.x < PDIM) {
        int p = blockIdx.x;
        float er = expf(llr[p]);
        float im = lim[p];
        float d  = expf(ldl[p]);
        float zr = -er * d, zi = im * d;
        float ea = expf(zr);
        float sz, cz; sincosf(zi, &sz, &cz);
        float ar = ea * cz, ai = ea * sz;
        float dr = -er, di = im;
        float den = dr * dr + di * di;
        float nr = ar - 1.0f, ni = ai;
        float cr = (nr * dr + ni * di) / den;
        float ci = (ni * dr - nr * di) / den;
        float br = Br[p * HDIM + h], bi = Bi[p * HDIM + h];
        W1t[(2 * p) * HDIM + h]     = f2bf(cr * br - ci * bi);
        W1t[(2 * p + 1) * HDIM + h] = f2bf(cr * bi + ci * br);
    } else if (blockIdx.x < 2 * PDIM) {
        int p = blockIdx.x - PDIM;
        W2t[h * (2 * PDIM) + 2 * p]     = f2bf(Cr[h * PDIM + p]);
        W2t[h * (2 * PDIM) + 2 * p + 1] = f2bf(-Ci[h * PDIM + p]);
    } else {
        int p = h;
        float er = expf(llr[p]);
        float im = lim[p];
        float d  = expf(ldl[p]);
        float zr = -er * d, zi = im * d;
        float ea = expf(zr);
        float sz, cz; sincosf(zi, &sz, &cz);
        float ar = ea * cz, ai = ea * sz;
        float dr = -er, di = im;
        float den = dr * dr + di * di;
        float nr = ar - 1.0f, ni = ai;
        float cr = (nr * dr + ni * di) / den;
        float ci = (ni * dr - nr * di) / den;
        float eC = expf((float)CHLEN * zr);
        float sC, cC;
        sincosf((float)CHLEN * zi, &sC, &cC);
        par[2 * p]            = ar;
        par[2 * p + 1]        = ai;
        par[512 + 2 * p]      = cr;
        par[512 + 2 * p + 1]  = ci;
        par[1024 + 2 * p]     = eC * cC;
        par[1024 + 2 * p + 1] = eC * sC;
    }
}

// ---------------- fused LayerNorm -> bf16 h ----------------
__global__ void ln_k(const float* __restrict__ u, unsigned short* __restrict__ hbf,
                     const float* __restrict__ gamma, const float* __restrict__ beta) {
    __shared__ float gS[HDIM], bS[HDIM];
    int t = threadIdx.x;
    gS[t] = gamma[t]; bS[t] = beta[t];
    int lane = t & 63, wv = t >> 6;
    int row = blockIdx.x * 4 + wv;
    float4 v = *(const float4*)(u + (size_t)row * HDIM + lane * 4);
    float s  = v.x + v.y + v.z + v.w;
    float sq = v.x * v.x + v.y * v.y + v.z * v.z + v.w * v.w;
    #pragma unroll
    for (int o = 1; o < 64; o <<= 1) { s += __shfl_xor(s, o); sq += __shfl_xor(sq, o); }
    float mu = s * (1.0f / HDIM);
    float rs = rsqrtf(sq * (1.0f / HDIM) - mu * mu + 1e-5f);
    __syncthreads();
    int c = lane * 4;
    ushort4 o;
    o.x = f2bf((v.x - mu) * rs * gS[c + 0] + bS[c + 0]);
    o.y = f2bf((v.y - mu) * rs * gS[c + 1] + bS[c + 1]);
    o.z = f2bf((v.z - mu) * rs * gS[c + 2] + bS[c + 2]);
    o.w = f2bf((v.w - mu) * rs * gS[c + 3] + bS[c + 3]);
    *(ushort4*)(hbf + (size_t)row * HDIM + c) = o;
}

// ---------------- GEMM1: Bu[32768][512] = h[32768][256] @ W1t^T ----------------
// Pure-VGPR, zero-LDS, zero-barrier kernel. Block = 64 M-rows x full N=512,
// 8 waves; wave w owns the 64x64 output tile at N-offset 64w. Both A (hbf)
// and B (W1t, 256 KB -> per-XCD-L2-resident after first block) fragments are
// loaded directly global->VGPR as bf16x8 in MFMA layout. The K-loop (8 steps)
// is fully unrolled with plain indexed loads -> 64 independent VMEM ops the
// compiler hoists to whatever prefetch depth the VGPR budget allows (no
// barrier fences anywhere; this is the regime where hipcc schedules well).
// A-addresses are identical across the 8 waves -> L1 broadcast reuse.
__launch_bounds__(512, 4)
__global__ void gemm1_k(const unsigned short* __restrict__ A,
                        const unsigned short* __restrict__ W1t,
                        unsigned short* __restrict__ Bu) {
    const int t = threadIdx.x;
    const int lane = t & 63, w = t >> 6;
    const int bm = blockIdx.x;                 // 64-row M tile
    const int mrow = lane & 15, cch = lane >> 4;

    const unsigned short* gA = A   + (size_t)(bm * 64 + mrow) * HDIM + cch * 8;
    const unsigned short* gW = W1t + (size_t)(w * 64 + mrow) * HDIM + cch * 8;

    f32x4 acc[4][4] = {};
    #pragma unroll
    for (int tt = 0; tt < HDIM / 32; tt++) {   // 8 steps, no barriers, no LDS
        bf16x8 fa[4], fb[4];
        #pragma unroll
        for (int i = 0; i < 4; i++)
            fa[i] = *(const bf16x8*)(gA + (size_t)i * 16 * HDIM + tt * 32);
        #pragma unroll
        for (int j = 0; j < 4; j++)
            fb[j] = *(const bf16x8*)(gW + (size_t)j * 16 * HDIM + tt * 32);
        #pragma unroll
        for (int i = 0; i < 4; i++)
            #pragma unroll
            for (int j = 0; j < 4; j++)
                acc[i][j] = __builtin_amdgcn_mfma_f32_16x16x32_bf16(fa[i], fb[j], acc[i][j], 0, 0, 0);
    }

    // C/D layout (verified): col = lane&15, row = (lane>>4)*4 + reg
    const int r0 = (lane >> 4) * 4, c0 = lane & 15;
    #pragma unroll
    for (int i = 0; i < 4; i++) {
        #pragma unroll
        for (int r = 0; r < 4; r++) {
            const size_t rowoff = (size_t)(bm * 64 + i * 16 + r0 + r) * 512;
            #pragma unroll
            for (int j = 0; j < 4; j++)
                Bu[rowoff + w * 64 + j * 16 + c0] = f2bf(acc[i][j][r]);
        }
    }
}

// ---------------- chunked diagonal complex scan, passes 1+2 (unchanged) ----------------
__global__ void scan_reduce_k(const unsigned short* __restrict__ Bu,
                              const float* __restrict__ par, float* __restrict__ last) {
    int t = threadIdx.x;
    int lane = t & 63, g = t >> 6;
    int c = blockIdx.x * 4 + g, b = blockIdx.y;
    int p0 = lane * 4;
    float4 a01 = *(const float4*)(par + 2 * p0);       // ar0 ai0 ar1 ai1
    float4 a23 = *(const float4*)(par + 2 * p0 + 4);   // ar2 ai2 ar3 ai3
    float ar[4] = {a01.x, a01.z, a23.x, a23.z};
    float ai[4] = {a01.y, a01.w, a23.y, a23.w};
    float xr[4] = {0.f, 0.f, 0.f, 0.f}, xi[4] = {0.f, 0.f, 0.f, 0.f};
    const uint4* q = (const uint4*)(Bu + ((size_t)b * LSEQ + (size_t)c * CHLEN) * 512) + lane;
    #pragma unroll 8
    for (int j = 0; j < CHLEN; j++) {
        uint4 v = q[(size_t)j * 64];   // row stride 512 bf16 = 64 uint4
        unsigned int vv[4] = {v.x, v.y, v.z, v.w};
        #pragma unroll
        for (int k = 0; k < 4; k++) {
            float vr = bf2f(vv[k] & 0xFFFFu), vi = bf2f(vv[k] >> 16);
            float nr = fmaf(ar[k], xr[k], fmaf(-ai[k], xi[k], vr));
            float ni = fmaf(ar[k], xi[k], fmaf(ai[k], xr[k], vi));
            xr[k] = nr; xi[k] = ni;
        }
    }
    float* lp = last + ((size_t)b * NCHUNK + c) * 512 + 2 * p0;
    *(float4*)lp       = make_float4(xr[0], xi[0], xr[1], xi[1]);
    *(float4*)(lp + 4) = make_float4(xr[2], xi[2], xr[3], xi[3]);
}

__global__ void scan_carry_k(const float* __restrict__ last, float* __restrict__ prefix,
                             const float* __restrict__ par) {
    int p = threadIdx.x, b = blockIdx.x;
    float Ar = par[1024 + 2 * p], Ai = par[1024 + 2 * p + 1];  // a^CHLEN
    float Pr = 0.0f, Pi = 0.0f;
    const float2* lp = (const float2*)(last + (size_t)b * NCHUNK * 512) + p;
    float2* pp = (float2*)(prefix + (size_t)b * NCHUNK * 512) + p;
    for (int c0 = 0; c0 < NCHUNK; c0 += 16) {
        float2 v[16];
        #pragma unroll
        for (int j = 0; j < 16; j++) v[j] = lp[(size_t)(c0 + j) * 256];
        #pragma unroll
        for (int j = 0; j < 16; j++) {
            pp[(size_t)(c0 + j) * 256] = make_float2(Pr, Pi);
            float nr = fmaf(Ar, Pr, fmaf(-Ai, Pi, v[j].x));
            float ni = fmaf(Ar, Pi, fmaf(Ai, Pr, v[j].y));
            Pr = nr; Pi = ni;
        }
    }
}

// ---------------- fused scan_apply + GEMM2 ----------------
// Block = one (batch b, chunk c) = 32 rows x full N=256. Thread p: load its
// Bu column (32 independent coalesced uint loads), run the recurrence in
// registers seeded from prefix, pack x (bf16, same f2bf rounding) into
// XOR-swizzled LDS Xs. ONE barrier. Then out[32][256] = u + gelu(x @ W2t^T):
// fa from Xs (2-way-max bank alias = free), fb DIRECT global->VGPR from the
// L2-resident W2t (no staging, no barriers, fully unrolled 16-step K-loop ->
// compiler-depth prefetch). x never touches global memory. LDS = 32 KB only
// -> 5 blocks/CU.
__launch_bounds__(256, 4)
__global__ void apply_gemm2_k(const unsigned short* __restrict__ Bu,
                              const float* __restrict__ par,
                              const float* __restrict__ prefix,
                              const unsigned short* __restrict__ W2t,
                              const float* __restrict__ u, float* __restrict__ out) {
    __shared__ __align__(16) unsigned short Xs[32 * 512];     // 32 KB, swizzled
    const int t = threadIdx.x;
    const int lane = t & 63, w = t >> 6;
    const int c = blockIdx.x, b = blockIdx.y;
    const size_t row0 = (size_t)b * LSEQ + (size_t)c * CHLEN;

    // ---------- apply phase: thread p owns complex column p ----------
    {
        const int p = t;
        const unsigned int* q = (const unsigned int*)(Bu + row0 * 512) + p;
        unsigned int vv[32];
        #pragma unroll
        for (int j = 0; j < 32; j++) vv[j] = q[(size_t)j * 256];
        const float2 P = ((const float2*)(prefix + ((size_t)b * NCHUNK + c) * 512))[p];
        const float ar = par[2 * p], ai = par[2 * p + 1];
        float xr = P.x, xi = P.y;
        #pragma unroll
        for (int j = 0; j < 32; j++) {
            float vr = bf2f(vv[j] & 0xFFFFu), vi = bf2f(vv[j] >> 16);
            float nr = fmaf(ar, xr, fmaf(-ai, xi, vr));
            float ni = fmaf(ar, xi, fmaf(ai, xr, vi));
            xr = nr; xi = ni;
            unsigned int pk = (unsigned int)f2bf(xr) | ((unsigned int)f2bf(xi) << 16);
            // Xs[j][.]: 16B-chunk = p>>2, swizzle ^= j&7, word = p&3
            *(unsigned int*)&Xs[j * 512 + ((((p >> 2) ^ (j & 7)) << 3) + (p & 3) * 2)] = pk;
        }
    }

    const int mrow = lane & 15, cch = lane >> 4;
    const unsigned short* gW = W2t + (size_t)(w * 64 + mrow) * 512 + cch * 8;

    f32x4 acc[2][4] = {};
    __syncthreads();         // Xs complete (the only barrier)

    #pragma unroll
    for (int tt = 0; tt < 16; tt++) {          // K=512, no barriers, no staging
        bf16x8 fa[2], fb[4];
        #pragma unroll
        for (int i = 0; i < 2; i++) {
            const int r = i * 16 + mrow;
            fa[i] = *(const bf16x8*)&Xs[r * 512 + (((tt * 4 + cch) ^ (r & 7)) << 3)];
        }
        #pragma unroll
        for (int j = 0; j < 4; j++)
            fb[j] = *(const bf16x8*)(gW + (size_t)j * 16 * 512 + tt * 32);
        #pragma unroll
        for (int i = 0; i < 2; i++)
            #pragma unroll
            for (int j = 0; j < 4; j++)
                acc[i][j] = __builtin_amdgcn_mfma_f32_16x16x32_bf16(fa[i], fb[j], acc[i][j], 0, 0, 0);
    }

    // epilogue: out = u + gelu(acc), fp32. Wave w owns out-cols 64w..64w+63.
    const int r0 = (lane >> 4) * 4, c0 = lane & 15;
    #pragma unroll
    for (int i = 0; i < 2; i++) {
        #pragma unroll
        for (int r = 0; r < 4; r++) {
            const size_t rowoff = (row0 + i * 16 + r0 + r) * HDIM;
            #pragma unroll
            for (int j = 0; j < 4; j++) {
                const int col = w * 64 + j * 16 + c0;
                float y = acc[i][j][r];
                float z = 0.7978845608f * fmaf(0.044715f * y * y, y, y);
                float e = __expf(2.0f * z);
                float th = 1.0f - 2.0f / (e + 1.0f);
                float g = 0.5f * y * (1.0f + th);
                out[rowoff + col] = u[rowoff + col] + g;
            }
        }
    }
}

extern "C" void kernel_launch(void* const* d_in, const int* in_sizes, int n_in,
                              void* d_out, int out_size, void* d_ws, size_t ws_size,
                              hipStream_t stream) {
    const float* u   = (const float*)d_in[0];
    const float* llr = (const float*)d_in[1];
    const float* lim = (const float*)d_in[2];
    const float* Br  = (const float*)d_in[3];
    const float* Bi  = (const float*)d_in[4];
    const float* Cr  = (const float*)d_in[5];
    const float* Ci  = (const float*)d_in[6];
    const float* ldl = (const float*)d_in[7];
    const float* gam = (const float*)d_in[8];
    const float* bet = (const float*)d_in[9];
    float* out = (float*)d_out;

    float* ws     = (float*)d_ws;
    float* par    = ws;                                     // 2048 floats
    float* last   = ws + 2048;                              // 8*128*512 floats (2 MB)
    float* prefix = last + (size_t)BATCH * NCHUNK * 512;    // 2 MB
    unsigned short* W1t = (unsigned short*)(prefix + (size_t)BATCH * NCHUNK * 512);
    unsigned short* W2t = W1t + 512 * HDIM;                 // [256][512]
    unsigned short* hbf = W2t + HDIM * 512;                 // [32768][256] bf16
    unsigned short* Bu  = hbf + (size_t)MTOT * HDIM;        // [32768][512] bf16

    ln_k<<<MTOT / 4, 256, 0, stream>>>(u, hbf, gam, bet);
    wpack_k<<<2 * PDIM + 1, HDIM, 0, stream>>>(llr, lim, ldl, Br, Bi, Cr, Ci, W1t, W2t, par);

    // GEMM1: pure-VGPR, barrier-free
    gemm1_k<<<MTOT / 64, 512, 0, stream>>>(hbf, W1t, Bu);

    scan_reduce_k<<<dim3(NCHUNK / 4, BATCH), 256, 0, stream>>>(Bu, par, last);
    scan_carry_k<<<BATCH, PDIM, 0, stream>>>(last, prefix, par);

    // fused scan_apply + GEMM2: x lives only in LDS; direct-global W2t fragments
    apply_gemm2_k<<<dim3(NCHUNK, BATCH), 256, 0, stream>>>(Bu, par, prefix, W2t, u, out);
}

// Round 6
// 163.573 us; speedup vs baseline: 1.2638x; 1.1832x over previous
//
#include <hip/hip_runtime.h>
#include <math.h>

#define HDIM 256
#define PDIM 256
#define BATCH 8
#define LSEQ 4096
#define MTOT (BATCH * LSEQ)   // 32768
#define NCHUNK 128
#define CHLEN 32              // NCHUNK*CHLEN == LSEQ

typedef __attribute__((ext_vector_type(8))) short bf16x8;   // 8 bf16 = 4 VGPRs
typedef __attribute__((ext_vector_type(4))) float f32x4;

__device__ __forceinline__ unsigned short f2bf(float f) {
    union { float f; unsigned int u; } v; v.f = f;
    unsigned int r = v.u + 0x7FFFu + ((v.u >> 16) & 1u);   // RNE
    return (unsigned short)(r >> 16);
}
__device__ __forceinline__ float bf2f(unsigned int lo16) {
    union { unsigned int u; float f; } v; v.u = lo16 << 16;
    return v.f;
}

// async global->LDS, 16B per lane; LDS dest is wave-uniform base + lane*16
__device__ __forceinline__ void gload_lds16(const void* g, void* l) {
    __builtin_amdgcn_global_load_lds(
        (const __attribute__((address_space(1))) void*)g,
        (__attribute__((address_space(3))) void*)l, 16, 0, 0);
}

// ---------------- merged setup: par + W1t + W2t in one launch ----------------
// par floats: [0:512) a  [512:1024) coef  [1024:1536) a^CHLEN  (interleaved r,i)
// W1t[n][k]: n=2p -> Re(coef_p * B_tilde[p][k]); n=2p+1 -> Im. (bf16, [512][256])
// W2t[h][2p] = Cr[h][p]; W2t[h][2p+1] = -Ci[h][p]. (bf16, [256][512])
__global__ void wpack_k(const float* __restrict__ llr, const float* __restrict__ lim,
                        const float* __restrict__ ldl,
                        const float* __restrict__ Br, const float* __restrict__ Bi,
                        const float* __restrict__ Cr, const float* __restrict__ Ci,
                        unsigned short* __restrict__ W1t, unsigned short* __restrict__ W2t,
                        float* __restrict__ par) {
    int h = threadIdx.x;
    if (blockIdx.x < PDIM) {
        int p = blockIdx.x;
        float er = expf(llr[p]);
        float im = lim[p];
        float d  = expf(ldl[p]);
        float zr = -er * d, zi = im * d;
        float ea = expf(zr);
        float sz, cz; sincosf(zi, &sz, &cz);
        float ar = ea * cz, ai = ea * sz;
        float dr = -er, di = im;
        float den = dr * dr + di * di;
        float nr = ar - 1.0f, ni = ai;
        float cr = (nr * dr + ni * di) / den;
        float ci = (ni * dr - nr * di) / den;
        float br = Br[p * HDIM + h], bi = Bi[p * HDIM + h];
        W1t[(2 * p) * HDIM + h]     = f2bf(cr * br - ci * bi);
        W1t[(2 * p + 1) * HDIM + h] = f2bf(cr * bi + ci * br);
    } else if (blockIdx.x < 2 * PDIM) {
        int p = blockIdx.x - PDIM;
        W2t[h * (2 * PDIM) + 2 * p]     = f2bf(Cr[h * PDIM + p]);
        W2t[h * (2 * PDIM) + 2 * p + 1] = f2bf(-Ci[h * PDIM + p]);
    } else {
        int p = h;
        float er = expf(llr[p]);
        float im = lim[p];
        float d  = expf(ldl[p]);
        float zr = -er * d, zi = im * d;
        float ea = expf(zr);
        float sz, cz; sincosf(zi, &sz, &cz);
        float ar = ea * cz, ai = ea * sz;
        float dr = -er, di = im;
        float den = dr * dr + di * di;
        float nr = ar - 1.0f, ni = ai;
        float cr = (nr * dr + ni * di) / den;
        float ci = (ni * dr - nr * di) / den;
        float eC = expf((float)CHLEN * zr);
        float sC, cC;
        sincosf((float)CHLEN * zi, &sC, &cC);
        par[2 * p]            = ar;
        par[2 * p + 1]        = ai;
        par[512 + 2 * p]      = cr;
        par[512 + 2 * p + 1]  = ci;
        par[1024 + 2 * p]     = eC * cC;
        par[1024 + 2 * p + 1] = eC * sC;
    }
}

// ---------------- fused LayerNorm -> bf16 h ----------------
__global__ void ln_k(const float* __restrict__ u, unsigned short* __restrict__ hbf,
                     const float* __restrict__ gamma, const float* __restrict__ beta) {
    __shared__ float gS[HDIM], bS[HDIM];
    int t = threadIdx.x;
    gS[t] = gamma[t]; bS[t] = beta[t];
    int lane = t & 63, wv = t >> 6;
    int row = blockIdx.x * 4 + wv;
    float4 v = *(const float4*)(u + (size_t)row * HDIM + lane * 4);
    float s  = v.x + v.y + v.z + v.w;
    float sq = v.x * v.x + v.y * v.y + v.z * v.z + v.w * v.w;
    #pragma unroll
    for (int o = 1; o < 64; o <<= 1) { s += __shfl_xor(s, o); sq += __shfl_xor(sq, o); }
    float mu = s * (1.0f / HDIM);
    float rs = rsqrtf(sq * (1.0f / HDIM) - mu * mu + 1e-5f);
    __syncthreads();
    int c = lane * 4;
    ushort4 o;
    o.x = f2bf((v.x - mu) * rs * gS[c + 0] + bS[c + 0]);
    o.y = f2bf((v.y - mu) * rs * gS[c + 1] + bS[c + 1]);
    o.z = f2bf((v.z - mu) * rs * gS[c + 2] + bS[c + 2]);
    o.w = f2bf((v.w - mu) * rs * gS[c + 3] + bS[c + 3]);
    *(ushort4*)(hbf + (size_t)row * HDIM + c) = o;
}

// ---------------- bf16 MFMA GEMM: C[M][N] = A[M][K] * Bt[N][K] ----------------
// R1 structure (best measured) + T4 counted vmcnt + T5 setprio:
//   prologue: stage tile0 -> buf0
//   iter t:   stage tile t+1 -> buf[cur^1]     (4 gload_lds per wave)
//             s_waitcnt vmcnt(4)               (wait ONLY tile-t loads; t+1's
//                                               4 loads stay in flight ACROSS
//                                               the barrier - T4, m218)
//             s_barrier; ds_read + 16 MFMA (setprio 1) ; s_barrier
// Correctness: each wave waits its own 4 tile-t loads before its barrier ->
// after the barrier all of tile t is in LDS. Trailing barrier = all waves
// consumed buf[cur] (MFMA data-dep implies ds_reads completed) before the
// next iteration's stage overwrites it. Last iter peels to vmcnt(0).
// sched_barrier(0) fences per rule #18 (hipcc hoists past asm waitcnt).
// Bank-conflict involution (rule #21) and XCD-chunked remap as before.
// MODE 0: store bf16. MODE 1: out fp32 = u + gelu(acc).
template <int MODE, int K>
__launch_bounds__(256, 2)
__global__ void mfma_gemm_k(const unsigned short* __restrict__ A,
                            const unsigned short* __restrict__ B,
                            void* __restrict__ outv,
                            const float* __restrict__ u,
                            int N) {
    __shared__ __align__(16) unsigned short As[2][128 * 32];
    __shared__ __align__(16) unsigned short Bs[2][128 * 32];
    const int t = threadIdx.x;

    // XCD-aware remap (8 XCDs, hw round-robins blockIdx across XCDs)
    const int nbn  = (int)gridDim.x;
    const int flat = (int)blockIdx.y * nbn + (int)blockIdx.x;
    const int nwg  = nbn * (int)gridDim.y;
    const int tile = (flat & 7) * (nwg >> 3) + (flat >> 3);
    const int bn = tile % nbn, bm = tile / nbn;

    const int lane = t & 63, w = t >> 6;

    // staging addresses: wave w stages rows 32w..32w+31 of both tiles
    const int srow   = 32 * w + (lane >> 2);
    const int schunk = (lane & 3) ^ ((lane >> 3) & 3);
    const unsigned short* gA = A + (size_t)(bm * 128 + srow) * K + schunk * 8;
    const unsigned short* gB = B + (size_t)(bn * 128 + srow) * K + schunk * 8;
    const int l0 = (32 * w) * 32;
    const int l1 = (32 * w + 16) * 32;

    const int wm = (w & 1) * 64;
    const int wn = (w >> 1) * 64;
    const int mrow = lane & 15;
    const int rsw  = (mrow >> 1) & 3;          // == (row>>1)&3 for all fragment rows
    const int cch  = lane >> 4;                // k-chunk this lane group reads
    const int fcol = ((cch ^ rsw) * 8);        // swizzled element offset in row

    f32x4 acc[4][4] = {};
    constexpr int NT = K / 32;

    // prologue: stage tile 0 into buf 0 (4 loads in flight)
    gload_lds16(gA,          &As[0][l0]);
    gload_lds16(gA + 16 * K, &As[0][l1]);
    gload_lds16(gB,          &Bs[0][l0]);
    gload_lds16(gB + 16 * K, &Bs[0][l1]);

    #pragma unroll
    for (int tt = 0; tt < NT; ++tt) {
        const int cur = tt & 1;
        if (tt + 1 < NT) {
            const int k0 = (tt + 1) * 32;
            gload_lds16(gA + k0,          &As[cur ^ 1][l0]);
            gload_lds16(gA + 16 * K + k0, &As[cur ^ 1][l1]);
            gload_lds16(gB + k0,          &Bs[cur ^ 1][l0]);
            gload_lds16(gB + 16 * K + k0, &Bs[cur ^ 1][l1]);
            asm volatile("s_waitcnt vmcnt(4)" ::: "memory");   // tile t landed; t+1 in flight
        } else {
            asm volatile("s_waitcnt vmcnt(0)" ::: "memory");   // last tile: drain
        }
        __builtin_amdgcn_sched_barrier(0);
        __builtin_amdgcn_s_barrier();
        __builtin_amdgcn_sched_barrier(0);

        bf16x8 fa[4], fb[4];
        #pragma unroll
        for (int i = 0; i < 4; i++) {
            fa[i] = *(const bf16x8*)&As[cur][(wm + i * 16 + mrow) * 32 + fcol];
            fb[i] = *(const bf16x8*)&Bs[cur][(wn + i * 16 + mrow) * 32 + fcol];
        }
        __builtin_amdgcn_s_setprio(1);
        #pragma unroll
        for (int i = 0; i < 4; i++)
            #pragma unroll
            for (int j = 0; j < 4; j++)
                acc[i][j] = __builtin_amdgcn_mfma_f32_16x16x32_bf16(fa[i], fb[j], acc[i][j], 0, 0, 0);
        __builtin_amdgcn_s_setprio(0);
        __builtin_amdgcn_sched_barrier(0);
        if (tt + 1 < NT) __builtin_amdgcn_s_barrier();   // reads of buf[cur] done before overwrite
    }

    // C/D layout (m89-verified): col = lane&15, row = (lane>>4)*4 + reg
    const int r0 = (lane >> 4) * 4;
    const int c0 = lane & 15;
    #pragma unroll
    for (int i = 0; i < 4; i++) {
        #pragma unroll
        for (int r = 0; r < 4; r++) {
            const size_t rowoff = (size_t)(bm * 128 + wm + i * 16 + r0 + r) * N;
            #pragma unroll
            for (int j = 0; j < 4; j++) {
                const int col_g = bn * 128 + wn + j * 16 + c0;
                float y = acc[i][j][r];
                if (MODE == 0) {
                    ((unsigned short*)outv)[rowoff + col_g] = f2bf(y);
                } else {
                    float z = 0.7978845608f * fmaf(0.044715f * y * y, y, y);
                    float e = __expf(2.0f * z);
                    float th = 1.0f - 2.0f / (e + 1.0f);
                    float g = 0.5f * y * (1.0f + th);
                    ((float*)outv)[rowoff + col_g] = u[rowoff + col_g] + g;
                }
            }
        }
    }
}

// ---------------- chunked diagonal complex scan over bf16 Bu ----------------
// Each 64-lane group owns one (chunk,batch) row-set; lane owns 4 consecutive p
// -> uint4 (16B) coalesced loads/stores. Per-p arithmetic identical to scalar.
__global__ void scan_reduce_k(const unsigned short* __restrict__ Bu,
                              const float* __restrict__ par, float* __restrict__ last) {
    int t = threadIdx.x;
    int lane = t & 63, g = t >> 6;
    int c = blockIdx.x * 4 + g, b = blockIdx.y;
    int p0 = lane * 4;
    float4 a01 = *(const float4*)(par + 2 * p0);       // ar0 ai0 ar1 ai1
    float4 a23 = *(const float4*)(par + 2 * p0 + 4);   // ar2 ai2 ar3 ai3
    float ar[4] = {a01.x, a01.z, a23.x, a23.z};
    float ai[4] = {a01.y, a01.w, a23.y, a23.w};
    float xr[4] = {0.f, 0.f, 0.f, 0.f}, xi[4] = {0.f, 0.f, 0.f, 0.f};
    const uint4* q = (const uint4*)(Bu + ((size_t)b * LSEQ + (size_t)c * CHLEN) * 512) + lane;
    #pragma unroll 8
    for (int j = 0; j < CHLEN; j++) {
        uint4 v = q[(size_t)j * 64];   // row stride 512 bf16 = 64 uint4
        unsigned int vv[4] = {v.x, v.y, v.z, v.w};
        #pragma unroll
        for (int k = 0; k < 4; k++) {
            float vr = bf2f(vv[k] & 0xFFFFu), vi = bf2f(vv[k] >> 16);
            float nr = fmaf(ar[k], xr[k], fmaf(-ai[k], xi[k], vr));
            float ni = fmaf(ar[k], xi[k], fmaf(ai[k], xr[k], vi));
            xr[k] = nr; xi[k] = ni;
        }
    }
    float* lp = last + ((size_t)b * NCHUNK + c) * 512 + 2 * p0;
    *(float4*)lp       = make_float4(xr[0], xi[0], xr[1], xi[1]);
    *(float4*)(lp + 4) = make_float4(xr[2], xi[2], xr[3], xi[3]);
}

__global__ void scan_carry_k(const float* __restrict__ last, float* __restrict__ prefix,
                             const float* __restrict__ par) {
    int p = threadIdx.x, b = blockIdx.x;
    float Ar = par[1024 + 2 * p], Ai = par[1024 + 2 * p + 1];  // a^CHLEN
    float Pr = 0.0f, Pi = 0.0f;
    const float2* lp = (const float2*)(last + (size_t)b * NCHUNK * 512) + p;
    float2* pp = (float2*)(prefix + (size_t)b * NCHUNK * 512) + p;
    for (int c0 = 0; c0 < NCHUNK; c0 += 16) {
        float2 v[16];
        #pragma unroll
        for (int j = 0; j < 16; j++) v[j] = lp[(size_t)(c0 + j) * 256];
        #pragma unroll
        for (int j = 0; j < 16; j++) {
            pp[(size_t)(c0 + j) * 256] = make_float2(Pr, Pi);
            float nr = fmaf(Ar, Pr, fmaf(-Ai, Pi, v[j].x));
            float ni = fmaf(Ar, Pi, fmaf(Ai, Pr, v[j].y));
            Pr = nr; Pi = ni;
        }
    }
}

__global__ void scan_apply_k(unsigned short* __restrict__ Bu, const float* __restrict__ par,
                             const float* __restrict__ prefix) {
    int t = threadIdx.x;
    int lane = t & 63, g = t >> 6;
    int c = blockIdx.x * 4 + g, b = blockIdx.y;
    int p0 = lane * 4;
    float4 a01 = *(const float4*)(par + 2 * p0);
    float4 a23 = *(const float4*)(par + 2 * p0 + 4);
    float ar[4] = {a01.x, a01.z, a23.x, a23.z};
    float ai[4] = {a01.y, a01.w, a23.y, a23.w};
    const float* pf = prefix + ((size_t)b * NCHUNK + c) * 512 + 2 * p0;
    float4 P01 = *(const float4*)pf;
    float4 P23 = *(const float4*)(pf + 4);
    float xr[4] = {P01.x, P01.z, P23.x, P23.z};
    float xi[4] = {P01.y, P01.w, P23.y, P23.w};
    uint4* q = (uint4*)(Bu + ((size_t)b * LSEQ + (size_t)c * CHLEN) * 512) + lane;
    #pragma unroll 8
    for (int j = 0; j < CHLEN; j++) {
        uint4 v = q[(size_t)j * 64];
        unsigned int vv[4] = {v.x, v.y, v.z, v.w};
        #pragma unroll
        for (int k = 0; k < 4; k++) {
            float vr = bf2f(vv[k] & 0xFFFFu), vi = bf2f(vv[k] >> 16);
            float nr = fmaf(ar[k], xr[k], fmaf(-ai[k], xi[k], vr));
            float ni = fmaf(ar[k], xi[k], fmaf(ai[k], xr[k], vi));
            xr[k] = nr; xi[k] = ni;
            vv[k] = (unsigned int)f2bf(nr) | ((unsigned int)f2bf(ni) << 16);
        }
        uint4 o; o.x = vv[0]; o.y = vv[1]; o.z = vv[2]; o.w = vv[3];
        q[(size_t)j * 64] = o;
    }
}

extern "C" void kernel_launch(void* const* d_in, const int* in_sizes, int n_in,
                              void* d_out, int out_size, void* d_ws, size_t ws_size,
                              hipStream_t stream) {
    const float* u   = (const float*)d_in[0];
    const float* llr = (const float*)d_in[1];
    const float* lim = (const float*)d_in[2];
    const float* Br  = (const float*)d_in[3];
    const float* Bi  = (const float*)d_in[4];
    const float* Cr  = (const float*)d_in[5];
    const float* Ci  = (const float*)d_in[6];
    const float* ldl = (const float*)d_in[7];
    const float* gam = (const float*)d_in[8];
    const float* bet = (const float*)d_in[9];
    float* out = (float*)d_out;

    float* ws     = (float*)d_ws;
    float* par    = ws;                                     // 2048 floats
    float* last   = ws + 2048;                              // 8*128*512 floats (2 MB)
    float* prefix = last + (size_t)BATCH * NCHUNK * 512;    // 2 MB
    unsigned short* W1t = (unsigned short*)(prefix + (size_t)BATCH * NCHUNK * 512);
    unsigned short* W2t = W1t + 512 * HDIM;                 // [256][512]
    unsigned short* hbf = W2t + HDIM * 512;                 // [32768][256] bf16
    unsigned short* Bu  = hbf + (size_t)MTOT * HDIM;        // [32768][512] bf16 (in-place -> x)

    ln_k<<<MTOT / 4, 256, 0, stream>>>(u, hbf, gam, bet);
    wpack_k<<<2 * PDIM + 1, HDIM, 0, stream>>>(llr, lim, ldl, Br, Bi, Cr, Ci, W1t, W2t, par);

    // GEMM1: Bu[32768][512] = h[32768][256] @ W1t^T   (bf16 in, bf16 out)
    mfma_gemm_k<0, HDIM><<<dim3(512 / 128, MTOT / 128), 256, 0, stream>>>(
        hbf, W1t, (void*)Bu, nullptr, 512);

    scan_reduce_k<<<dim3(NCHUNK / 4, BATCH), 256, 0, stream>>>(Bu, par, last);
    scan_carry_k<<<BATCH, PDIM, 0, stream>>>(last, prefix, par);
    scan_apply_k<<<dim3(NCHUNK / 4, BATCH), 256, 0, stream>>>(Bu, par, prefix);

    // GEMM2: out[32768][256] = u + gelu( x[32768][512] @ W2t^T )   (fp32 out)
    mfma_gemm_k<1, 512><<<dim3(HDIM / 128, MTOT / 128), 256, 0, stream>>>(
        Bu, W2t, (void*)out, u, HDIM);
}

// Round 7
// 163.158 us; speedup vs baseline: 1.2670x; 1.0025x over previous
//
#include <hip/hip_runtime.h>
#include <math.h>

#define HDIM 256
#define PDIM 256
#define BATCH 8
#define LSEQ 4096
#define MTOT (BATCH * LSEQ)   // 32768
#define NCHUNK 128
#define CHLEN 32              // NCHUNK*CHLEN == LSEQ

typedef __attribute__((ext_vector_type(8))) short bf16x8;   // 8 bf16 = 4 VGPRs
typedef __attribute__((ext_vector_type(4))) float f32x4;

__device__ __forceinline__ unsigned short f2bf(float f) {
    union { float f; unsigned int u; } v; v.f = f;
    unsigned int r = v.u + 0x7FFFu + ((v.u >> 16) & 1u);   // RNE
    return (unsigned short)(r >> 16);
}
__device__ __forceinline__ float bf2f(unsigned int lo16) {
    union { unsigned int u; float f; } v; v.u = lo16 << 16;
    return v.f;
}

// async global->LDS, 16B per lane; LDS dest is wave-uniform base + lane*16
__device__ __forceinline__ void gload_lds16(const void* g, void* l) {
    __builtin_amdgcn_global_load_lds(
        (const __attribute__((address_space(1))) void*)g,
        (__attribute__((address_space(3))) void*)l, 16, 0, 0);
}

// ---------------- merged setup: par + W1t + W2t in one launch ----------------
// par floats: [0:512) a  [512:1024) coef  [1024:1536) a^CHLEN  (interleaved r,i)
// W1t[n][k]: n=2p -> Re(coef_p * B_tilde[p][k]); n=2p+1 -> Im. (bf16, [512][256])
// W2t[h][2p] = Cr[h][p]; W2t[h][2p+1] = -Ci[h][p]. (bf16, [256][512])
__global__ void wpack_k(const float* __restrict__ llr, const float* __restrict__ lim,
                        const float* __restrict__ ldl,
                        const float* __restrict__ Br, const float* __restrict__ Bi,
                        const float* __restrict__ Cr, const float* __restrict__ Ci,
                        unsigned short* __restrict__ W1t, unsigned short* __restrict__ W2t,
                        float* __restrict__ par) {
    int h = threadIdx.x;
    if (blockIdx.x < PDIM) {
        int p = blockIdx.x;
        float er = expf(llr[p]);
        float im = lim[p];
        float d  = expf(ldl[p]);
        float zr = -er * d, zi = im * d;
        float ea = expf(zr);
        float sz, cz; sincosf(zi, &sz, &cz);
        float ar = ea * cz, ai = ea * sz;
        float dr = -er, di = im;
        float den = dr * dr + di * di;
        float nr = ar - 1.0f, ni = ai;
        float cr = (nr * dr + ni * di) / den;
        float ci = (ni * dr - nr * di) / den;
        float br = Br[p * HDIM + h], bi = Bi[p * HDIM + h];
        W1t[(2 * p) * HDIM + h]     = f2bf(cr * br - ci * bi);
        W1t[(2 * p + 1) * HDIM + h] = f2bf(cr * bi + ci * br);
    } else if (blockIdx.x < 2 * PDIM) {
        int p = blockIdx.x - PDIM;
        W2t[h * (2 * PDIM) + 2 * p]     = f2bf(Cr[h * PDIM + p]);
        W2t[h * (2 * PDIM) + 2 * p + 1] = f2bf(-Ci[h * PDIM + p]);
    } else {
        int p = h;
        float er = expf(llr[p]);
        float im = lim[p];
        float d  = expf(ldl[p]);
        float zr = -er * d, zi = im * d;
        float ea = expf(zr);
        float sz, cz; sincosf(zi, &sz, &cz);
        float ar = ea * cz, ai = ea * sz;
        float dr = -er, di = im;
        float den = dr * dr + di * di;
        float nr = ar - 1.0f, ni = ai;
        float cr = (nr * dr + ni * di) / den;
        float ci = (ni * dr - nr * di) / den;
        float eC = expf((float)CHLEN * zr);
        float sC, cC;
        sincosf((float)CHLEN * zi, &sC, &cC);
        par[2 * p]            = ar;
        par[2 * p + 1]        = ai;
        par[512 + 2 * p]      = cr;
        par[512 + 2 * p + 1]  = ci;
        par[1024 + 2 * p]     = eC * cC;
        par[1024 + 2 * p + 1] = eC * sC;
    }
}

// ---------------- fused LayerNorm -> bf16 h ----------------
__global__ void ln_k(const float* __restrict__ u, unsigned short* __restrict__ hbf,
                     const float* __restrict__ gamma, const float* __restrict__ beta) {
    __shared__ float gS[HDIM], bS[HDIM];
    int t = threadIdx.x;
    gS[t] = gamma[t]; bS[t] = beta[t];
    int lane = t & 63, wv = t >> 6;
    int row = blockIdx.x * 4 + wv;
    float4 v = *(const float4*)(u + (size_t)row * HDIM + lane * 4);
    float s  = v.x + v.y + v.z + v.w;
    float sq = v.x * v.x + v.y * v.y + v.z * v.z + v.w * v.w;
    #pragma unroll
    for (int o = 1; o < 64; o <<= 1) { s += __shfl_xor(s, o); sq += __shfl_xor(sq, o); }
    float mu = s * (1.0f / HDIM);
    float rs = rsqrtf(sq * (1.0f / HDIM) - mu * mu + 1e-5f);
    __syncthreads();
    int c = lane * 4;
    ushort4 o;
    o.x = f2bf((v.x - mu) * rs * gS[c + 0] + bS[c + 0]);
    o.y = f2bf((v.y - mu) * rs * gS[c + 1] + bS[c + 1]);
    o.z = f2bf((v.z - mu) * rs * gS[c + 2] + bS[c + 2]);
    o.w = f2bf((v.w - mu) * rs * gS[c + 3] + bS[c + 3]);
    *(ushort4*)(hbf + (size_t)row * HDIM + c) = o;
}

// ---------------- GEMM1 (R6, unchanged): Bu = h @ W1t^T ----------------
// R1 structure + T4 counted vmcnt + T5 setprio. See R6 notes.
template <int MODE, int K>
__launch_bounds__(256, 2)
__global__ void mfma_gemm_k(const unsigned short* __restrict__ A,
                            const unsigned short* __restrict__ B,
                            void* __restrict__ outv,
                            const float* __restrict__ u,
                            int N) {
    __shared__ __align__(16) unsigned short As[2][128 * 32];
    __shared__ __align__(16) unsigned short Bs[2][128 * 32];
    const int t = threadIdx.x;

    const int nbn  = (int)gridDim.x;
    const int flat = (int)blockIdx.y * nbn + (int)blockIdx.x;
    const int nwg  = nbn * (int)gridDim.y;
    const int tile = (flat & 7) * (nwg >> 3) + (flat >> 3);
    const int bn = tile % nbn, bm = tile / nbn;

    const int lane = t & 63, w = t >> 6;

    const int srow   = 32 * w + (lane >> 2);
    const int schunk = (lane & 3) ^ ((lane >> 3) & 3);
    const unsigned short* gA = A + (size_t)(bm * 128 + srow) * K + schunk * 8;
    const unsigned short* gB = B + (size_t)(bn * 128 + srow) * K + schunk * 8;
    const int l0 = (32 * w) * 32;
    const int l1 = (32 * w + 16) * 32;

    const int wm = (w & 1) * 64;
    const int wn = (w >> 1) * 64;
    const int mrow = lane & 15;
    const int rsw  = (mrow >> 1) & 3;
    const int cch  = lane >> 4;
    const int fcol = ((cch ^ rsw) * 8);

    f32x4 acc[4][4] = {};
    constexpr int NT = K / 32;

    gload_lds16(gA,          &As[0][l0]);
    gload_lds16(gA + 16 * K, &As[0][l1]);
    gload_lds16(gB,          &Bs[0][l0]);
    gload_lds16(gB + 16 * K, &Bs[0][l1]);

    #pragma unroll
    for (int tt = 0; tt < NT; ++tt) {
        const int cur = tt & 1;
        if (tt + 1 < NT) {
            const int k0 = (tt + 1) * 32;
            gload_lds16(gA + k0,          &As[cur ^ 1][l0]);
            gload_lds16(gA + 16 * K + k0, &As[cur ^ 1][l1]);
            gload_lds16(gB + k0,          &Bs[cur ^ 1][l0]);
            gload_lds16(gB + 16 * K + k0, &Bs[cur ^ 1][l1]);
            asm volatile("s_waitcnt vmcnt(4)" ::: "memory");
        } else {
            asm volatile("s_waitcnt vmcnt(0)" ::: "memory");
        }
        __builtin_amdgcn_sched_barrier(0);
        __builtin_amdgcn_s_barrier();
        __builtin_amdgcn_sched_barrier(0);

        bf16x8 fa[4], fb[4];
        #pragma unroll
        for (int i = 0; i < 4; i++) {
            fa[i] = *(const bf16x8*)&As[cur][(wm + i * 16 + mrow) * 32 + fcol];
            fb[i] = *(const bf16x8*)&Bs[cur][(wn + i * 16 + mrow) * 32 + fcol];
        }
        __builtin_amdgcn_s_setprio(1);
        #pragma unroll
        for (int i = 0; i < 4; i++)
            #pragma unroll
            for (int j = 0; j < 4; j++)
                acc[i][j] = __builtin_amdgcn_mfma_f32_16x16x32_bf16(fa[i], fb[j], acc[i][j], 0, 0, 0);
        __builtin_amdgcn_s_setprio(0);
        __builtin_amdgcn_sched_barrier(0);
        if (tt + 1 < NT) __builtin_amdgcn_s_barrier();
    }

    const int r0 = (lane >> 4) * 4;
    const int c0 = lane & 15;
    #pragma unroll
    for (int i = 0; i < 4; i++) {
        #pragma unroll
        for (int r = 0; r < 4; r++) {
            const size_t rowoff = (size_t)(bm * 128 + wm + i * 16 + r0 + r) * N;
            #pragma unroll
            for (int j = 0; j < 4; j++) {
                const int col_g = bn * 128 + wn + j * 16 + c0;
                float y = acc[i][j][r];
                if (MODE == 0) {
                    ((unsigned short*)outv)[rowoff + col_g] = f2bf(y);
                } else {
                    float z = 0.7978845608f * fmaf(0.044715f * y * y, y, y);
                    float e = __expf(2.0f * z);
                    float th = 1.0f - 2.0f / (e + 1.0f);
                    float g = 0.5f * y * (1.0f + th);
                    ((float*)outv)[rowoff + col_g] = u[rowoff + col_g] + g;
                }
            }
        }
    }
}

// ---------------- scan passes 1+2 (unchanged) ----------------
__global__ void scan_reduce_k(const unsigned short* __restrict__ Bu,
                              const float* __restrict__ par, float* __restrict__ last) {
    int t = threadIdx.x;
    int lane = t & 63, g = t >> 6;
    int c = blockIdx.x * 4 + g, b = blockIdx.y;
    int p0 = lane * 4;
    float4 a01 = *(const float4*)(par + 2 * p0);
    float4 a23 = *(const float4*)(par + 2 * p0 + 4);
    float ar[4] = {a01.x, a01.z, a23.x, a23.z};
    float ai[4] = {a01.y, a01.w, a23.y, a23.w};
    float xr[4] = {0.f, 0.f, 0.f, 0.f}, xi[4] = {0.f, 0.f, 0.f, 0.f};
    const uint4* q = (const uint4*)(Bu + ((size_t)b * LSEQ + (size_t)c * CHLEN) * 512) + lane;
    #pragma unroll 8
    for (int j = 0; j < CHLEN; j++) {
        uint4 v = q[(size_t)j * 64];
        unsigned int vv[4] = {v.x, v.y, v.z, v.w};
        #pragma unroll
        for (int k = 0; k < 4; k++) {
            float vr = bf2f(vv[k] & 0xFFFFu), vi = bf2f(vv[k] >> 16);
            float nr = fmaf(ar[k], xr[k], fmaf(-ai[k], xi[k], vr));
            float ni = fmaf(ar[k], xi[k], fmaf(ai[k], xr[k], vi));
            xr[k] = nr; xi[k] = ni;
        }
    }
    float* lp = last + ((size_t)b * NCHUNK + c) * 512 + 2 * p0;
    *(float4*)lp       = make_float4(xr[0], xi[0], xr[1], xi[1]);
    *(float4*)(lp + 4) = make_float4(xr[2], xi[2], xr[3], xi[3]);
}

__global__ void scan_carry_k(const float* __restrict__ last, float* __restrict__ prefix,
                             const float* __restrict__ par) {
    int p = threadIdx.x, b = blockIdx.x;
    float Ar = par[1024 + 2 * p], Ai = par[1024 + 2 * p + 1];
    float Pr = 0.0f, Pi = 0.0f;
    const float2* lp = (const float2*)(last + (size_t)b * NCHUNK * 512) + p;
    float2* pp = (float2*)(prefix + (size_t)b * NCHUNK * 512) + p;
    for (int c0 = 0; c0 < NCHUNK; c0 += 16) {
        float2 v[16];
        #pragma unroll
        for (int j = 0; j < 16; j++) v[j] = lp[(size_t)(c0 + j) * 256];
        #pragma unroll
        for (int j = 0; j < 16; j++) {
            pp[(size_t)(c0 + j) * 256] = make_float2(Pr, Pi);
            float nr = fmaf(Ar, Pr, fmaf(-Ai, Pi, v[j].x));
            float ni = fmaf(Ar, Pi, fmaf(Ai, Pr, v[j].y));
            Pr = nr; Pi = ni;
        }
    }
}

// ---------------- fused scan_apply + GEMM2 ----------------
// Block = one (b,c) chunk: 32 rows x N=256. Phase A (R5-verified math):
// thread p runs the recurrence for column p in registers seeded from prefix,
// packs x as bf16 into XOR-swizzled Xs. ONE barrier. Phase B: wave w owns
// out-cols 64w..64w+63 and stages ITS OWN 64 W2t rows per k-slice via
// gload_lds16 (R6 involution) -> staging is WAVE-PRIVATE, so the 16-step
// K-loop needs NO s_barrier at all: per step {4 gload (next) ; vmcnt(4) ;
// 8 ds_read ; 8 MFMA} with sched_barrier(0) fences (rule #18). Within-wave
// double-buffer WAR is safe: each step's MFMAs (lgkm-waited on its ds_reads)
// precede the next stage issue in pinned program order. x never touches HBM.
// LDS = 32 (Xs) + 32 (Bs dbuf) = 64 KB -> 2 blocks/CU.
__launch_bounds__(256, 2)
__global__ void apply_gemm2_k(const unsigned short* __restrict__ Bu,
                              const float* __restrict__ par,
                              const float* __restrict__ prefix,
                              const unsigned short* __restrict__ W2t,
                              const float* __restrict__ u, float* __restrict__ out) {
    __shared__ __align__(16) unsigned short Xs[32 * 512];     // 32 KB, swizzled
    __shared__ __align__(16) unsigned short Bs[2][256 * 32];  // 2 x 16 KB
    const int t = threadIdx.x;
    const int lane = t & 63, w = t >> 6;
    const int c = blockIdx.x, b = blockIdx.y;
    const size_t row0 = (size_t)b * LSEQ + (size_t)c * CHLEN;

    // wave-private W2t staging (R6 involution): call m stages rows 64w+16m+(lane>>2)
    const int schunk = (lane & 3) ^ ((lane >> 3) & 3);
    const unsigned short* gW = W2t + (size_t)(w * 64 + (lane >> 2)) * 512 + schunk * 8;

    // tile-0 prefetch: latency hides under phase A
    #pragma unroll
    for (int m = 0; m < 4; m++)
        gload_lds16(gW + (size_t)m * 16 * 512, &Bs[0][(w * 64 + m * 16) * 32]);

    // ---------- phase A: thread p = t owns complex column p ----------
    {
        const unsigned int* q = (const unsigned int*)(Bu + row0 * 512) + t;
        unsigned int vv[32];
        #pragma unroll
        for (int j = 0; j < 32; j++) vv[j] = q[(size_t)j * 256];
        const float2 P = ((const float2*)(prefix + ((size_t)b * NCHUNK + c) * 512))[t];
        const float ar = par[2 * t], ai = par[2 * t + 1];
        float xr = P.x, xi = P.y;
        #pragma unroll
        for (int j = 0; j < 32; j++) {
            float vr = bf2f(vv[j] & 0xFFFFu), vi = bf2f(vv[j] >> 16);
            float nr = fmaf(ar, xr, fmaf(-ai, xi, vr));
            float ni = fmaf(ar, xi, fmaf(ai, xr, vi));
            xr = nr; xi = ni;
            unsigned int pk = (unsigned int)f2bf(xr) | ((unsigned int)f2bf(xi) << 16);
            // Xs[j][.]: 16B-chunk = p>>2, swizzle ^= j&7, word = p&3
            *(unsigned int*)&Xs[j * 512 + ((((t >> 2) ^ (j & 7)) << 3) + (t & 3) * 2)] = pk;
        }
    }

    const int mrow = lane & 15;
    const int rsw  = (mrow >> 1) & 3;
    const int cch  = lane >> 4;
    const int fcol = (cch ^ rsw) * 8;

    f32x4 acc[2][4] = {};
    __syncthreads();            // Xs complete; drains tile-0 staging too

    #pragma unroll
    for (int tt = 0; tt < 16; tt++) {          // K=512; NO s_barrier in loop
        const int cur = tt & 1;
        if (tt + 1 < 16) {
            const int k0 = (tt + 1) * 32;
            #pragma unroll
            for (int m = 0; m < 4; m++)
                gload_lds16(gW + (size_t)m * 16 * 512 + k0,
                            &Bs[cur ^ 1][(w * 64 + m * 16) * 32]);
            asm volatile("s_waitcnt vmcnt(4)" ::: "memory");   // tile tt landed; tt+1 in flight
        } else {
            asm volatile("s_waitcnt vmcnt(0)" ::: "memory");
        }
        __builtin_amdgcn_sched_barrier(0);

        bf16x8 fa[2], fb[4];
        #pragma unroll
        for (int i = 0; i < 2; i++) {
            const int r = i * 16 + mrow;
            fa[i] = *(const bf16x8*)&Xs[r * 512 + (((tt * 4 + cch) ^ (r & 7)) << 3)];
        }
        #pragma unroll
        for (int j = 0; j < 4; j++)
            fb[j] = *(const bf16x8*)&Bs[cur][(w * 64 + j * 16 + mrow) * 32 + fcol];
        __builtin_amdgcn_s_setprio(1);
        #pragma unroll
        for (int i = 0; i < 2; i++)
            #pragma unroll
            for (int j = 0; j < 4; j++)
                acc[i][j] = __builtin_amdgcn_mfma_f32_16x16x32_bf16(fa[i], fb[j], acc[i][j], 0, 0, 0);
        __builtin_amdgcn_s_setprio(0);
        __builtin_amdgcn_sched_barrier(0);     // pin: next stage stays after these MFMAs
    }

    // epilogue: out = u + gelu(acc). Wave w owns out-cols 64w..64w+63.
    const int r0 = (lane >> 4) * 4, c0 = lane & 15;
    #pragma unroll
    for (int i = 0; i < 2; i++) {
        #pragma unroll
        for (int r = 0; r < 4; r++) {
            const size_t rowoff = (row0 + i * 16 + r0 + r) * HDIM;
            #pragma unroll
            for (int j = 0; j < 4; j++) {
                const int col = w * 64 + j * 16 + c0;
                float y = acc[i][j][r];
                float z = 0.7978845608f * fmaf(0.044715f * y * y, y, y);
                float e = __expf(2.0f * z);
                float th = 1.0f - 2.0f / (e + 1.0f);
                float g = 0.5f * y * (1.0f + th);
                out[rowoff + col] = u[rowoff + col] + g;
            }
        }
    }
}

extern "C" void kernel_launch(void* const* d_in, const int* in_sizes, int n_in,
                              void* d_out, int out_size, void* d_ws, size_t ws_size,
                              hipStream_t stream) {
    const float* u   = (const float*)d_in[0];
    const float* llr = (const float*)d_in[1];
    const float* lim = (const float*)d_in[2];
    const float* Br  = (const float*)d_in[3];
    const float* Bi  = (const float*)d_in[4];
    const float* Cr  = (const float*)d_in[5];
    const float* Ci  = (const float*)d_in[6];
    const float* ldl = (const float*)d_in[7];
    const float* gam = (const float*)d_in[8];
    const float* bet = (const float*)d_in[9];
    float* out = (float*)d_out;

    float* ws     = (float*)d_ws;
    float* par    = ws;                                     // 2048 floats
    float* last   = ws + 2048;                              // 2 MB
    float* prefix = last + (size_t)BATCH * NCHUNK * 512;    // 2 MB
    unsigned short* W1t = (unsigned short*)(prefix + (size_t)BATCH * NCHUNK * 512);
    unsigned short* W2t = W1t + 512 * HDIM;                 // [256][512]
    unsigned short* hbf = W2t + HDIM * 512;                 // [32768][256] bf16
    unsigned short* Bu  = hbf + (size_t)MTOT * HDIM;        // [32768][512] bf16

    ln_k<<<MTOT / 4, 256, 0, stream>>>(u, hbf, gam, bet);
    wpack_k<<<2 * PDIM + 1, HDIM, 0, stream>>>(llr, lim, ldl, Br, Bi, Cr, Ci, W1t, W2t, par);

    // GEMM1: Bu[32768][512] = h[32768][256] @ W1t^T   (bf16 in, bf16 out)
    mfma_gemm_k<0, HDIM><<<dim3(512 / 128, MTOT / 128), 256, 0, stream>>>(
        hbf, W1t, (void*)Bu, nullptr, 512);

    scan_reduce_k<<<dim3(NCHUNK / 4, BATCH), 256, 0, stream>>>(Bu, par, last);
    scan_carry_k<<<BATCH, PDIM, 0, stream>>>(last, prefix, par);

    // fused scan_apply + GEMM2: x lives only in LDS; wave-private barrier-free K-loop
    apply_gemm2_k<<<dim3(NCHUNK, BATCH), 256, 0, stream>>>(Bu, par, prefix, W2t, u, out);
}